// Round 4
// baseline (366.003 us; speedup 1.0000x reference)
//
#include <hip/hip_runtime.h>
#include <stdint.h>

typedef unsigned short u16;
typedef __attribute__((ext_vector_type(8))) short short8;    // 8 bf16 (4 VGPRs)
typedef __attribute__((ext_vector_type(16))) float f32x16;

#define ATTN_SCALE 0.08838834764831845f   // 1/sqrt(128)

__device__ __forceinline__ u16 f2bf(float f) {
  union { float f; uint32_t u; } a; a.f = f;
  return (u16)((a.u + 0x7fffu + ((a.u >> 16) & 1u)) >> 16);   // RNE
}

__device__ __forceinline__ void async16(const u16* g, u16* lds) {
  __builtin_amdgcn_global_load_lds(
      (const __attribute__((address_space(1))) void*)g,
      (__attribute__((address_space(3))) void*)lds, 16, 0, 0);
}

// ---------------- fp32 -> bf16 conversion (8 elems/thread) ----------------
__global__ void cvt_kernel(const float* __restrict__ src, u16* __restrict__ dst, int n8) {
  int i = blockIdx.x * 256 + threadIdx.x;
  if (i >= n8) return;
  const float4* s4 = (const float4*)src;
  float4 a = s4[2 * i], c = s4[2 * i + 1];
  union { u16 h[8]; uint4 v; } o;
  o.h[0] = f2bf(a.x); o.h[1] = f2bf(a.y); o.h[2] = f2bf(a.z); o.h[3] = f2bf(a.w);
  o.h[4] = f2bf(c.x); o.h[5] = f2bf(c.y); o.h[6] = f2bf(c.z); o.h[7] = f2bf(c.w);
  ((uint4*)dst)[i] = o.v;
}

__global__ void cvtw_kernel(const float* __restrict__ w0, const float* __restrict__ w1,
                            const float* __restrict__ w2, u16* __restrict__ dst) {
  int z = blockIdx.y;
  const float* src = (z == 0) ? w0 : (z == 1) ? w1 : w2;
  int i = blockIdx.x * 256 + threadIdx.x;
  const float4* s4 = (const float4*)src;
  float4 a = s4[2 * i], c = s4[2 * i + 1];
  union { u16 h[8]; uint4 v; } o;
  o.h[0] = f2bf(a.x); o.h[1] = f2bf(a.y); o.h[2] = f2bf(a.z); o.h[3] = f2bf(a.w);
  o.h[4] = f2bf(c.x); o.h[5] = f2bf(c.y); o.h[6] = f2bf(c.z); o.h[7] = f2bf(c.w);
  ((uint4*)(dst + (size_t)z * 4194304))[i] = o.v;
}

// ---------------- QKV projection v2: 32x32x16 MFMA, dbuf-after-barrier ------
// C[4096,2048] = xb @ W.T + b ; z picks Q / K / V^T destination layout.
__global__ __launch_bounds__(256, 3) void qkv_gemm(
    const u16* __restrict__ xb, const u16* __restrict__ Wb,
    const float* __restrict__ bq, const float* __restrict__ bk, const float* __restrict__ bv,
    u16* __restrict__ qkv) {
  __shared__ __align__(16) u16 As[2][128 * 32];   // 8 KB x2
  __shared__ __align__(16) u16 Bs[2][128 * 32];
  const int z = blockIdx.z;
  const int n0 = blockIdx.x * 128, m0 = blockIdx.y * 128;
  const u16* Bw = Wb + (size_t)z * (2048u * 2048u);
  const float* bias = (z == 0) ? bq : (z == 1) ? bk : bv;
  u16* dst = qkv + (size_t)z * 8388608u;
  const int t = threadIdx.x, wave = t >> 6, lane = t & 63;
  const int wm = wave >> 1, wn = wave & 1, l31 = lane & 31, h = lane >> 5;

  // staging geometry: tile [128][32], 4x16B granules/row; 512 chunks, 2/thread
  const int cid0 = wave * 128 + lane;          // chunks cid0, cid0+64
  f32x16 acc[2][2];
#pragma unroll
  for (int i = 0; i < 2; ++i)
#pragma unroll
    for (int j = 0; j < 2; ++j)
#pragma unroll
      for (int r = 0; r < 16; ++r) acc[i][j][r] = 0.f;

#pragma unroll 1
  for (int n = 0; n < 64; ++n) {
    if (n == 0) {
      // prologue stage of chunk 0 into buf 0
#pragma unroll
      for (int p = 0; p < 2; ++p) {
        const int cid = cid0 + p * 64, row = cid >> 2, col = (cid & 3) * 8;
        async16(xb + (size_t)(m0 + row) * 2048 + col, &As[0][cid * 8]);
        async16(Bw + (size_t)(n0 + row) * 2048 + col, &Bs[0][cid * 8]);
      }
    }
    __syncthreads();                            // drains stage of chunk n
    const int cur = n & 1;
    if (n + 1 < 64) {                           // prefetch chunk n+1 (lands by next barrier)
      const int k1 = (n + 1) * 32;
#pragma unroll
      for (int p = 0; p < 2; ++p) {
        const int cid = cid0 + p * 64, row = cid >> 2, col = (cid & 3) * 8;
        async16(xb + (size_t)(m0 + row) * 2048 + k1 + col, &As[cur ^ 1][cid * 8]);
        async16(Bw + (size_t)(n0 + row) * 2048 + k1 + col, &Bs[cur ^ 1][cid * 8]);
      }
    }
#pragma unroll
    for (int ks = 0; ks < 2; ++ks) {
      short8 af[2], bf[2];
#pragma unroll
      for (int i = 0; i < 2; ++i)
        af[i] = *(const short8*)&As[cur][(wm * 64 + i * 32 + l31) * 32 + ks * 16 + h * 8];
#pragma unroll
      for (int j = 0; j < 2; ++j)
        bf[j] = *(const short8*)&Bs[cur][(wn * 64 + j * 32 + l31) * 32 + ks * 16 + h * 8];
#pragma unroll
      for (int i = 0; i < 2; ++i)
#pragma unroll
        for (int j = 0; j < 2; ++j)
          acc[i][j] = __builtin_amdgcn_mfma_f32_32x32x16_bf16(af[i], bf[j], acc[i][j], 0, 0, 0);
    }
  }

  // C layout (32x32, m74/m101): col(n)=l31, row(m) = 8g + 4h + rr, reg=4g+rr
#pragma unroll
  for (int j = 0; j < 2; ++j) {
    const int col = n0 + wn * 64 + j * 32 + l31;
    const float bb_ = bias[col];
    const int hh = col >> 7, hd = col & 127;
#pragma unroll
    for (int i = 0; i < 2; ++i) {
#pragma unroll
      for (int g = 0; g < 4; ++g) {
        const int lbase = m0 + wm * 64 + i * 32 + 8 * g + 4 * h;
        const int bb = lbase >> 11, l0 = lbase & 2047;
        if (z == 2) {
          union { u16 q[4]; ushort2 d[2]; } pk;
#pragma unroll
          for (int rr = 0; rr < 4; ++rr) pk.q[rr] = f2bf(acc[i][j][4 * g + rr] + bb_);
          *(uint2*)&dst[((size_t)(bb * 16 + hh) * 128 + hd) * 2048 + l0] = *(uint2*)pk.q;
        } else {
#pragma unroll
          for (int rr = 0; rr < 4; ++rr)
            dst[((size_t)(bb * 16 + hh) * 2048 + (l0 + rr)) * 128 + hd] =
                f2bf(acc[i][j][4 * g + rr] + bb_);
        }
      }
    }
  }
}

// ---------------- attention v3: Tk=64 double-buffered, dbuf-after-barrier ----
__global__ __launch_bounds__(256, 2) void attn_kernel(
    const u16* __restrict__ Qg,   // [32][2048][128]
    const u16* __restrict__ Kg,   // [32][2048][128]
    const u16* __restrict__ Vtg,  // [32][128][2048]
    float* __restrict__ out) {    // [2][2048][2048] fp32
  __shared__ __align__(16) u16 Ks[2][64 * 128];   // 16 KB x2, swizzled g^(row&15)
  __shared__ __align__(16) u16 Vs[2][128 * 64];   // 16 KB x2, swizzled g^(row&7)
  const int bh = blockIdx.y, q0 = blockIdx.x * 128;
  const int t = threadIdx.x, wave = t >> 6, lane = t & 63;
  const int l31 = lane & 31, h = lane >> 5;
  const u16* Qp = Qg + (size_t)bh * 262144;
  const u16* Kp = Kg + (size_t)bh * 262144;
  const u16* Vp = Vtg + (size_t)bh * 262144;
  const int b = bh >> 4, hd = bh & 15;
  const int qrow = q0 + wave * 32 + l31;

  short8 qf[8];
#pragma unroll
  for (int s = 0; s < 8; ++s)
    qf[s] = *(const short8*)&Qp[(size_t)qrow * 128 + s * 16 + h * 8];

  f32x16 oac[4];
#pragma unroll
  for (int dt = 0; dt < 4; ++dt)
#pragma unroll
    for (int r = 0; r < 16; ++r) oac[dt][r] = 0.f;
  float den = 0.f;
  const int cidK = wave * 256 + lane;    // 1024 K-chunks, 4/thread (+64 steps)

#pragma unroll 1
  for (int n = 0; n < 32; ++n) {
    if (n == 0) {
#pragma unroll
      for (int p = 0; p < 4; ++p) {
        const int cid = cidK + p * 64;
        const int rk = cid >> 4, gk = (cid & 15) ^ (rk & 15);
        async16(Kp + (size_t)rk * 128 + gk * 8, &Ks[0][cid * 8]);
        const int rv = cid >> 3, gv = (cid & 7) ^ (rv & 7);
        async16(Vp + (size_t)rv * 2048 + gv * 8, &Vs[0][cid * 8]);
      }
    }
    __syncthreads();
    const int cur = n & 1;
    if (n + 1 < 32) {
      const int k1 = (n + 1) * 64;
#pragma unroll
      for (int p = 0; p < 4; ++p) {
        const int cid = cidK + p * 64;
        const int rk = cid >> 4, gk = (cid & 15) ^ (rk & 15);
        async16(Kp + (size_t)(k1 + rk) * 128 + gk * 8, &Ks[cur ^ 1][cid * 8]);
        const int rv = cid >> 3, gv = (cid & 7) ^ (rv & 7);
        async16(Vp + (size_t)rv * 2048 + k1 + gv * 8, &Vs[cur ^ 1][cid * 8]);
      }
    }

#pragma unroll
    for (int T = 0; T < 2; ++T) {
      const int krow = T * 32 + l31;
      f32x16 sc;
#pragma unroll
      for (int r = 0; r < 16; ++r) sc[r] = 0.f;
#pragma unroll
      for (int s = 0; s < 8; ++s) {
        const short8 kf = *(const short8*)&Ks[cur][(krow * 16 + (((2 * s + h) ^ (krow & 15)))) * 8];
        sc = __builtin_amdgcn_mfma_f32_32x32x16_bf16(kf, qf[s], sc, 0, 0, 0);
      }
      uint32_t pp[8];
#pragma unroll
      for (int i = 0; i < 8; ++i) {
        const float e0 = __expf(fminf(sc[2 * i] * ATTN_SCALE, 80.f));
        const float e1 = __expf(fminf(sc[2 * i + 1] * ATTN_SCALE, 80.f));
        den += e0 + e1;
        union { float f; uint32_t u; } u0, u1; u0.f = e0; u1.f = e1;
        pp[i] = ((u1.u + 0x8000u) & 0xffff0000u) | ((u0.u + 0x8000u) >> 16);
      }
      uint32_t x[8];
#pragma unroll
      for (int i = 0; i < 8; ++i) x[i] = __shfl_xor(pp[i], 32, 64);
#pragma unroll
      for (int ks = 0; ks < 2; ++ks) {
        const int o0 = ks * 4;
        union { uint32_t u[4]; short8 s8; } bfp;
        bfp.u[0] = h ? x[o0 + 2] : pp[o0 + 0];
        bfp.u[1] = h ? x[o0 + 3] : pp[o0 + 1];
        bfp.u[2] = h ? pp[o0 + 2] : x[o0 + 0];
        bfp.u[3] = h ? pp[o0 + 3] : x[o0 + 1];
        const int gk = T * 4 + ks * 2 + h;   // k-granule (0..7) in V tile
#pragma unroll
        for (int dt = 0; dt < 4; ++dt) {
          const int vrow = dt * 32 + l31;
          const short8 vf = *(const short8*)&Vs[cur][(vrow * 8 + (gk ^ (vrow & 7))) * 8];
          oac[dt] = __builtin_amdgcn_mfma_f32_32x32x16_bf16(vf, bfp.s8, oac[dt], 0, 0, 0);
        }
      }
    }
  }

  den += __shfl_xor(den, 32, 64);
  const float inv = 1.f / den;
#pragma unroll
  for (int dt = 0; dt < 4; ++dt) {
#pragma unroll
    for (int g4 = 0; g4 < 4; ++g4) {
      float4 o;
      o.x = oac[dt][4 * g4 + 0] * inv;
      o.y = oac[dt][4 * g4 + 1] * inv;
      o.z = oac[dt][4 * g4 + 2] * inv;
      o.w = oac[dt][4 * g4 + 3] * inv;
      const int d = dt * 32 + g4 * 8 + h * 4;
      *(float4*)&out[((size_t)(b * 2048 + qrow)) * 2048 + hd * 128 + d] = o;
    }
  }
}

extern "C" void kernel_launch(void* const* d_in, const int* in_sizes, int n_in,
                              void* d_out, int out_size, void* d_ws, size_t ws_size,
                              hipStream_t stream) {
  const float* x  = (const float*)d_in[0];
  const float* Wq = (const float*)d_in[1];
  const float* bq = (const float*)d_in[2];
  const float* Wk = (const float*)d_in[3];
  const float* bk = (const float*)d_in[4];
  const float* Wv = (const float*)d_in[5];
  const float* bv = (const float*)d_in[6];
  float* out = (float*)d_out;
  if (ws_size < 92274688u) return;

  u16* xb  = (u16*)d_ws;             // [4096][2048] bf16
  u16* Wb  = xb + 8388608;           // [3][2048][2048] bf16
  u16* qkv = Wb + 12582912;          // Q | K | V^T bf16

  cvt_kernel<<<4096, 256, 0, stream>>>(x, xb, 1048576);
  cvtw_kernel<<<dim3(2048, 3), 256, 0, stream>>>(Wq, Wk, Wv, Wb);
  qkv_gemm<<<dim3(16, 32, 3), 256, 0, stream>>>(xb, Wb, bq, bk, bv, qkv);
  attn_kernel<<<dim3(16, 32), 256, 0, stream>>>(qkv, qkv + 8388608, qkv + 16777216, out);
}

// Round 6
// 351.405 us; speedup vs baseline: 1.0415x; 1.0415x over previous
//
#include <hip/hip_runtime.h>
#include <stdint.h>

typedef unsigned short u16;
typedef __attribute__((ext_vector_type(8))) short short8;    // 8 bf16 (4 VGPRs)
typedef __attribute__((ext_vector_type(16))) float f32x16;

#define ATTN_SCALE 0.08838834764831845f   // 1/sqrt(128)

__device__ __forceinline__ u16 f2bf(float f) {
  union { float f; uint32_t u; } a; a.f = f;
  return (u16)((a.u + 0x7fffu + ((a.u >> 16) & 1u)) >> 16);   // RNE
}

__device__ __forceinline__ void async16(const u16* g, u16* lds) {
  __builtin_amdgcn_global_load_lds(
      (const __attribute__((address_space(1))) void*)g,
      (__attribute__((address_space(3))) void*)lds, 16, 0, 0);
}

// ---------------- fp32 -> bf16 conversion (8 elems/thread) ----------------
__global__ void cvt_kernel(const float* __restrict__ src, u16* __restrict__ dst, int n8) {
  int i = blockIdx.x * 256 + threadIdx.x;
  if (i >= n8) return;
  const float4* s4 = (const float4*)src;
  float4 a = s4[2 * i], c = s4[2 * i + 1];
  union { u16 h[8]; uint4 v; } o;
  o.h[0] = f2bf(a.x); o.h[1] = f2bf(a.y); o.h[2] = f2bf(a.z); o.h[3] = f2bf(a.w);
  o.h[4] = f2bf(c.x); o.h[5] = f2bf(c.y); o.h[6] = f2bf(c.z); o.h[7] = f2bf(c.w);
  ((uint4*)dst)[i] = o.v;
}

__global__ void cvtw_kernel(const float* __restrict__ w0, const float* __restrict__ w1,
                            const float* __restrict__ w2, u16* __restrict__ dst) {
  int z = blockIdx.y;
  const float* src = (z == 0) ? w0 : (z == 1) ? w1 : w2;
  int i = blockIdx.x * 256 + threadIdx.x;
  const float4* s4 = (const float4*)src;
  float4 a = s4[2 * i], c = s4[2 * i + 1];
  union { u16 h[8]; uint4 v; } o;
  o.h[0] = f2bf(a.x); o.h[1] = f2bf(a.y); o.h[2] = f2bf(a.z); o.h[3] = f2bf(a.w);
  o.h[4] = f2bf(c.x); o.h[5] = f2bf(c.y); o.h[6] = f2bf(c.z); o.h[7] = f2bf(c.w);
  ((uint4*)(dst + (size_t)z * 4194304))[i] = o.v;
}

// ---------------- QKV projection v3: conflict-free swizzled LDS -------------
// Tile [128][32] stored as 32 LDS rows x 256B; 16B-slot s: R=s>>4, j=s&15,
// u=j^(R&15), m=4R+(u>>2), c=u&3  <->  slot(m,c)=(m>>2)*16+((4*(m&3)+c)^((m>>2)&15)).
__global__ __launch_bounds__(256, 4) void qkv_gemm(
    const u16* __restrict__ xb, const u16* __restrict__ Wb,
    const float* __restrict__ bq, const float* __restrict__ bk, const float* __restrict__ bv,
    u16* __restrict__ qkv) {
  __shared__ __align__(16) u16 As[2][128 * 32];   // 8 KB x2
  __shared__ __align__(16) u16 Bs[2][128 * 32];
  const int z = blockIdx.z;
  const int n0 = blockIdx.x * 128, m0 = blockIdx.y * 128;
  const u16* Bw = Wb + (size_t)z * (2048u * 2048u);
  const float* bias = (z == 0) ? bq : (z == 1) ? bk : bv;
  u16* dst = qkv + (size_t)z * 8388608u;
  const int t = threadIdx.x, wave = t >> 6, lane = t & 63;
  const int wm = wave >> 1, wn = wave & 1, l31 = lane & 31, h = lane >> 5;

  // staging slots: s_p = p*256 + wave*64 + lane, p=0,1; precompute global offsets
  int soff[2], goff[2];
#pragma unroll
  for (int p = 0; p < 2; ++p) {
    const int s = p * 256 + wave * 64 + lane;
    const int R = s >> 4, j = s & 15, u = j ^ (R & 15);
    const int m = R * 4 + (u >> 2), c = u & 3;
    soff[p] = s * 8;                       // LDS elem offset
    goff[p] = m * 2048 + c * 8;            // global elem offset within tile rows
  }
  // frag-read precompute: m_i = wm*64 + i*32 + l31
  int fr16[2][2], fR15[2][2];              // [A/B][i]
  const int q4 = (l31 & 3) * 4;
#pragma unroll
  for (int i = 0; i < 2; ++i) {
    const int mA = wm * 64 + i * 32 + l31, mB = wn * 64 + i * 32 + l31;
    fr16[0][i] = (mA >> 2) * 16; fR15[0][i] = (mA >> 2) & 15;
    fr16[1][i] = (mB >> 2) * 16; fR15[1][i] = (mB >> 2) & 15;
  }

  f32x16 acc[2][2];
#pragma unroll
  for (int i = 0; i < 2; ++i)
#pragma unroll
    for (int j = 0; j < 2; ++j)
#pragma unroll
      for (int r = 0; r < 16; ++r) acc[i][j][r] = 0.f;

  const u16* Abase = xb + (size_t)m0 * 2048;
  const u16* Bbase = Bw + (size_t)n0 * 2048;

#pragma unroll 1
  for (int n = 0; n < 64; ++n) {
    if (n == 0) {
#pragma unroll
      for (int p = 0; p < 2; ++p) {
        async16(Abase + goff[p], &As[0][soff[p]]);
        async16(Bbase + goff[p], &Bs[0][soff[p]]);
      }
    }
    __syncthreads();                       // drains stage of tile n
    const int cur = n & 1;
    if (n + 1 < 64) {                      // prefetch tile n+1
      const int k1 = (n + 1) * 32;
#pragma unroll
      for (int p = 0; p < 2; ++p) {
        async16(Abase + goff[p] + k1, &As[cur ^ 1][soff[p]]);
        async16(Bbase + goff[p] + k1, &Bs[cur ^ 1][soff[p]]);
      }
    }
#pragma unroll
    for (int ks = 0; ks < 2; ++ks) {
      const int c = ks * 2 + h;
      short8 af[2], bf[2];
#pragma unroll
      for (int i = 0; i < 2; ++i) {
        af[i] = *(const short8*)&As[cur][(fr16[0][i] + ((q4 + c) ^ fR15[0][i])) * 8];
        bf[i] = *(const short8*)&Bs[cur][(fr16[1][i] + ((q4 + c) ^ fR15[1][i])) * 8];
      }
#pragma unroll
      for (int i = 0; i < 2; ++i)
#pragma unroll
        for (int j = 0; j < 2; ++j)
          acc[i][j] = __builtin_amdgcn_mfma_f32_32x32x16_bf16(af[i], bf[j], acc[i][j], 0, 0, 0);
    }
  }

  // C layout (32x32): col(n)=l31, row(m) = 8g + 4h + rr, reg = 4g + rr
#pragma unroll
  for (int j = 0; j < 2; ++j) {
    const int col = n0 + wn * 64 + j * 32 + l31;
    const float bb_ = bias[col];
    const int hh = col >> 7, hd = col & 127;
#pragma unroll
    for (int i = 0; i < 2; ++i) {
#pragma unroll
      for (int g = 0; g < 4; ++g) {
        const int lbase = m0 + wm * 64 + i * 32 + 8 * g + 4 * h;
        const int bb = lbase >> 11, l0 = lbase & 2047;
        if (z == 2) {
          union { u16 q[4]; uint2 d; } pk;
#pragma unroll
          for (int rr = 0; rr < 4; ++rr) pk.q[rr] = f2bf(acc[i][j][4 * g + rr] + bb_);
          *(uint2*)&dst[((size_t)(bb * 16 + hh) * 128 + hd) * 2048 + l0] = pk.d;
        } else {
#pragma unroll
          for (int rr = 0; rr < 4; ++rr)
            dst[((size_t)(bb * 16 + hh) * 2048 + (l0 + rr)) * 128 + hd] =
                f2bf(acc[i][j][4 * g + rr] + bb_);
        }
      }
    }
  }
}

// ---------------- attention v4b: Tk=64 single-buffer, 3 blocks/CU -----------
// Ks: 64x128 = 16 KB = 1024 slots; Vs: 128x64 = 16 KB = 1024 slots (4/thread EACH).
__global__ __launch_bounds__(256, 3) void attn_kernel(
    const u16* __restrict__ Qg,   // [32][2048][128]
    const u16* __restrict__ Kg,   // [32][2048][128]
    const u16* __restrict__ Vtg,  // [32][128][2048]
    float* __restrict__ out) {    // [2][2048][2048] fp32
  __shared__ __align__(16) u16 Ks[64 * 128];   // swizzled g^(row&15)
  __shared__ __align__(16) u16 Vs[128 * 64];   // swizzled g^(row&7)
  const int bh = blockIdx.y, q0 = blockIdx.x * 128;
  const int t = threadIdx.x, wave = t >> 6, lane = t & 63;
  const int l31 = lane & 31, h = lane >> 5;
  const u16* Qp = Qg + (size_t)bh * 262144;
  const u16* Kp = Kg + (size_t)bh * 262144;
  const u16* Vp = Vtg + (size_t)bh * 262144;
  const int b = bh >> 4, hd = bh & 15;
  const int qrow = q0 + wave * 32 + l31;

  short8 qf[8];
#pragma unroll
  for (int s = 0; s < 8; ++s)
    qf[s] = *(const short8*)&Qp[(size_t)qrow * 128 + s * 16 + h * 8];

  // staging precompute: K and V each 1024 slots -> 4 slots/thread
  int kOff[4], kSlot[4], vOff[4], vSlot[4];
#pragma unroll
  for (int p = 0; p < 4; ++p) {
    const int s = p * 256 + wave * 64 + lane;
    const int rk = s >> 4, gk = (s & 15) ^ (rk & 15);
    kSlot[p] = s * 8; kOff[p] = rk * 128 + gk * 8;
    const int rv = s >> 3, gv = (s & 7) ^ (rv & 7);
    vSlot[p] = s * 8; vOff[p] = rv * 2048 + gv * 8;
  }

  f32x16 oac[4];
#pragma unroll
  for (int dt = 0; dt < 4; ++dt)
#pragma unroll
    for (int r = 0; r < 16; ++r) oac[dt][r] = 0.f;
  float den = 0.f;

#pragma unroll 1
  for (int kt = 0; kt < 32; ++kt) {
    const int k0 = kt * 64;
    __syncthreads();                    // prev iter frag reads done
#pragma unroll
    for (int p = 0; p < 4; ++p) async16(Kp + (size_t)k0 * 128 + kOff[p], &Ks[kSlot[p]]);
#pragma unroll
    for (int p = 0; p < 4; ++p) async16(Vp + (size_t)k0 + vOff[p], &Vs[vSlot[p]]);
    __syncthreads();                    // staging visible

#pragma unroll
    for (int T = 0; T < 2; ++T) {
      const int krow = T * 32 + l31;
      f32x16 sc;
#pragma unroll
      for (int r = 0; r < 16; ++r) sc[r] = 0.f;
#pragma unroll
      for (int s = 0; s < 8; ++s) {
        const short8 kf = *(const short8*)&Ks[(krow * 16 + ((2 * s + h) ^ (krow & 15))) * 8];
        sc = __builtin_amdgcn_mfma_f32_32x32x16_bf16(kf, qf[s], sc, 0, 0, 0);
      }
      uint32_t pp[8];
#pragma unroll
      for (int i = 0; i < 8; ++i) {
        const float e0 = __expf(fminf(sc[2 * i] * ATTN_SCALE, 80.f));
        const float e1 = __expf(fminf(sc[2 * i + 1] * ATTN_SCALE, 80.f));
        den += e0 + e1;
        union { float f; uint32_t u; } u0, u1; u0.f = e0; u1.f = e1;
        pp[i] = ((u1.u + 0x8000u) & 0xffff0000u) | ((u0.u + 0x8000u) >> 16);
      }
      uint32_t x[8];
#pragma unroll
      for (int i = 0; i < 8; ++i) x[i] = __shfl_xor(pp[i], 32, 64);
#pragma unroll
      for (int ks = 0; ks < 2; ++ks) {
        const int o0 = ks * 4;
        union { uint32_t u[4]; short8 s8; } bfp;
        bfp.u[0] = h ? x[o0 + 2] : pp[o0 + 0];
        bfp.u[1] = h ? x[o0 + 3] : pp[o0 + 1];
        bfp.u[2] = h ? pp[o0 + 2] : x[o0 + 0];
        bfp.u[3] = h ? pp[o0 + 3] : x[o0 + 1];
        const int gk = T * 4 + ks * 2 + h;   // k-granule 0..7 in V tile
#pragma unroll
        for (int dt = 0; dt < 4; ++dt) {
          const int vrow = dt * 32 + l31;
          const short8 vf = *(const short8*)&Vs[(vrow * 8 + (gk ^ (vrow & 7))) * 8];
          oac[dt] = __builtin_amdgcn_mfma_f32_32x32x16_bf16(vf, bfp.s8, oac[dt], 0, 0, 0);
        }
      }
    }
  }

  den += __shfl_xor(den, 32, 64);
  const float inv = 1.f / den;
#pragma unroll
  for (int dt = 0; dt < 4; ++dt) {
#pragma unroll
    for (int g4 = 0; g4 < 4; ++g4) {
      float4 o;
      o.x = oac[dt][4 * g4 + 0] * inv;
      o.y = oac[dt][4 * g4 + 1] * inv;
      o.z = oac[dt][4 * g4 + 2] * inv;
      o.w = oac[dt][4 * g4 + 3] * inv;
      const int d = dt * 32 + g4 * 8 + h * 4;
      *(float4*)&out[((size_t)(b * 2048 + qrow)) * 2048 + hd * 128 + d] = o;
    }
  }
}

extern "C" void kernel_launch(void* const* d_in, const int* in_sizes, int n_in,
                              void* d_out, int out_size, void* d_ws, size_t ws_size,
                              hipStream_t stream) {
  const float* x  = (const float*)d_in[0];
  const float* Wq = (const float*)d_in[1];
  const float* bq = (const float*)d_in[2];
  const float* Wk = (const float*)d_in[3];
  const float* bk = (const float*)d_in[4];
  const float* Wv = (const float*)d_in[5];
  const float* bv = (const float*)d_in[6];
  float* out = (float*)d_out;
  if (ws_size < 92274688u) return;

  u16* xb  = (u16*)d_ws;             // [4096][2048] bf16
  u16* Wb  = xb + 8388608;           // [3][2048][2048] bf16
  u16* qkv = Wb + 12582912;          // Q | K | V^T bf16

  cvt_kernel<<<4096, 256, 0, stream>>>(x, xb, 1048576);
  cvtw_kernel<<<dim3(2048, 3), 256, 0, stream>>>(Wq, Wk, Wv, Wb);
  qkv_gemm<<<dim3(16, 32, 3), 256, 0, stream>>>(xb, Wb, bq, bk, bv, qkv);
  attn_kernel<<<dim3(16, 32), 256, 0, stream>>>(qkv, qkv + 8388608, qkv + 16777216, out);
}